// Round 1
// baseline (301.836 us; speedup 1.0000x reference)
//
#include <hip/hip_runtime.h>

// image2patch / im2col gather, LDS-staged + nontemporal output stores.
// R3: multi-band blocks (PB=3 patch-rows/block) + XCD-chunked swizzle.
//  - PB=3 stages 16 rows (16 KB) per block and emits 3 patch rows:
//    input load traffic drops 132 MB -> 86 MB (rows/image 504 -> 336).
//  - 5376 blocks, XCD-chunked swizzle: each XCD owns all 21 bands of 32
//    contiguous images, so the 4-row overlap between adjacent bands hits
//    the same XCD's private L2 instead of re-fetching from L3/HBM.
//  - Output side unchanged from R2 best: fully coalesced float4 NT stores.
//
//   input  : (32, 8, 256, 256) fp32 -> 256 images of 256x256
//   output : (256, 3969, 64) fp32; patch p: row0=4*(p/63), col0=4*(p%63)

constexpr unsigned NPDIM   = 63;            // patch positions per dim
constexpr unsigned PATCHES = NPDIM * NPDIM; // 3969
constexpr unsigned CHUNKS  = 16;            // float4 chunks per 8x8 patch
constexpr unsigned PB      = 3;             // patch rows per block (63 = 21*3)
constexpr unsigned BANDS   = NPDIM / PB;    // 21 blocks per image
constexpr unsigned SROWS   = 4 * PB + 4;    // 16 staged image rows
constexpr unsigned ROWPAD  = 65;            // LDS row stride in float4s

using fv4 = __attribute__((ext_vector_type(4))) float;

__global__ __launch_bounds__(256) void image2patch_kernel(
    const fv4* __restrict__ in4, fv4* __restrict__ out4) {
    __shared__ fv4 lds4[SROWS * ROWPAD];    // 16.6 KB -> still 8 blocks/CU

    // XCD-chunked swizzle (bijective: gridDim.x = 5376 divisible by 8).
    // HW round-robins blockIdx.x across the 8 XCDs; remap so XCD x gets a
    // contiguous work range (all bands of 32 images).
    unsigned cpx = gridDim.x >> 3;          // 672 blocks per XCD
    unsigned bid = blockIdx.x;
    unsigned swz = (bid & 7u) * cpx + (bid >> 3);

    unsigned n  = swz / BANDS;              // image index, 0..255
    unsigned pb = swz - n * BANDS;          // band index, 0..20

    unsigned t = threadIdx.x;

    // ---- stage 16-row band: rows 12*pb .. 12*pb+15, contiguous 4096 floats
    unsigned inbase4 = n * 16384u + pb * (12u * 64u);   // image=16384 f4, row=64 f4
    #pragma unroll
    for (unsigned k = 0; k < 4; ++k) {
        unsigned idx = k * 256u + t;        // 0..1023
        lds4[(idx >> 6) * ROWPAD + (idx & 63u)] = in4[inbase4 + idx];
    }
    __syncthreads();

    // ---- emit 3 patch rows x 63 patches = 3 x 1008 float4, coalesced, NT
    #pragma unroll
    for (unsigned prl = 0; prl < PB; ++prl) {
        unsigned outbase4 = (n * PATCHES + (pb * PB + prl) * NPDIM) * CHUNKS;
        #pragma unroll
        for (unsigned it = 0; it < 4; ++it) {
            unsigned i = it * 256u + t;
            if (i < NPDIM * CHUNKS) {               // 1008
                unsigned pc  = i >> 4;              // patch col, 0..62
                unsigned k4  = i & 15u;             // chunk in patch
                unsigned di  = k4 >> 1;             // row in patch, 0..7
                unsigned dj4 = k4 & 1u;             // half-row, 0..1
                fv4 v = lds4[(4u * prl + di) * ROWPAD + pc + dj4];
                __builtin_nontemporal_store(v, &out4[outbase4 + i]);
            }
        }
    }
}

extern "C" void kernel_launch(void* const* d_in, const int* in_sizes, int n_in,
                              void* d_out, int out_size, void* d_ws, size_t ws_size,
                              hipStream_t stream) {
    const fv4* in4 = (const fv4*)d_in[0];
    fv4* out4 = (fv4*)d_out;
    unsigned blocks = 256u * BANDS;         // 5376 = one block per (image, band)
    image2patch_kernel<<<blocks, 256, 0, stream>>>(in4, out4);
}

// Round 2
// 296.439 us; speedup vs baseline: 1.0182x; 1.0182x over previous
//
#include <hip/hip_runtime.h>

// image2patch / im2col gather, LDS-staged + NONTEMPORAL output stores.
// R4: exact revert to the best-measured kernel (R2, 293.9 us) as a
// machine-drift A/B. R3 (PB=3 bands + XCD swizzle) measured 301.8 us, but
// the harness poison fills ran 2.3% slower machine-wide that round
// (160.1 -> 163.5 us mean); normalized ratios dur/fill were 1.836 vs 1.846
// — identical within noise. This revert isolates the machine variable:
//   ~294 us + ~160 us fills  -> R3 was a real regression, keep R2 (this).
//   ~302 us + ~164 us fills  -> drift confirmed, R2==R3, at practical floor.
//
//   input  : (32, 8, 256, 256) fp32 -> 256 images of 256x256
//   output : (256, 3969, 64) fp32; patch p: row0=4*(p/63), col0=4*(p%63)
// One block per (n, pr): stage the 8-row band (8 KB) into LDS coalesced,
// barrier, emit 63 patches (1008 float4) fully coalesced from LDS.

constexpr unsigned NPDIM   = 63;            // patch positions per dim
constexpr unsigned PATCHES = NPDIM * NPDIM; // 3969
constexpr unsigned CHUNKS  = 16;            // float4 chunks per 8x8 patch
constexpr unsigned ROWPAD  = 65;            // LDS row stride in float4s

using fv4 = __attribute__((ext_vector_type(4))) float;

__global__ __launch_bounds__(256) void image2patch_kernel(
    const fv4* __restrict__ in4, fv4* __restrict__ out4) {
    __shared__ fv4 lds4[8 * ROWPAD];        // 8.3 KB

    unsigned bid = blockIdx.x;
    unsigned n   = bid / NPDIM;             // image index, 0..255
    unsigned pr  = bid - n * NPDIM;         // patch row, 0..62

    // ---- stage 8-row band: rows 4*pr .. 4*pr+7, contiguous 2048 floats ----
    unsigned inbase4 = n * 16384u + pr * 256u;  // image=16384 f4, row=64 f4
    unsigned t = threadIdx.x;
    {
        unsigned r0 = t >> 6, c0 = t & 63u;
        lds4[r0 * ROWPAD + c0] = in4[inbase4 + t];
        unsigned i1 = t + 256u;
        unsigned r1 = i1 >> 6, c1 = i1 & 63u;
        lds4[r1 * ROWPAD + c1] = in4[inbase4 + i1];
    }
    __syncthreads();

    // ---- emit 63 patches = 1008 float4, coalesced, nontemporal ----
    unsigned outbase4 = (n * PATCHES + pr * NPDIM) * CHUNKS;
    #pragma unroll
    for (unsigned it = 0; it < 4; ++it) {
        unsigned i = it * 256u + t;
        if (i < NPDIM * CHUNKS) {                   // 1008
            unsigned pc  = i >> 4;                  // patch col, 0..62
            unsigned k4  = i & 15u;                 // chunk in patch
            unsigned di  = k4 >> 1;                 // row in patch, 0..7
            unsigned dj4 = k4 & 1u;                 // half-row, 0..1
            fv4 v = lds4[di * ROWPAD + pc + dj4];
            __builtin_nontemporal_store(v, &out4[outbase4 + i]);
        }
    }
}

extern "C" void kernel_launch(void* const* d_in, const int* in_sizes, int n_in,
                              void* d_out, int out_size, void* d_ws, size_t ws_size,
                              hipStream_t stream) {
    const fv4* in4 = (const fv4*)d_in[0];
    fv4* out4 = (fv4*)d_out;
    unsigned blocks = 256u * NPDIM;   // one block per (image, patch-row) = 16128
    image2patch_kernel<<<blocks, 256, 0, stream>>>(in4, out4);
}